// Round 5
// baseline (192.179 us; speedup 1.0000x reference)
//
#include <hip/hip_runtime.h>
#include <hip/hip_bf16.h>
#include <cstdint>

#define N_IDE 4096
#define M_U   16384
#define D_DIM 256
#define EPSF  1e-12f
#define INV_M (1.0f / 16384.0f)

typedef _Float16 f16x8 __attribute__((ext_vector_type(8)));
typedef float    f32x4 __attribute__((ext_vector_type(4)));

// ---- async global->LDS 16B copy. LDS dest = wave-uniform base + lane*16. ----
__device__ __forceinline__ void gll16(const void* g, void* l) {
  __builtin_amdgcn_global_load_lds(
      (const __attribute__((address_space(1))) void*)(uintptr_t)g,
      (__attribute__((address_space(3))) void*)(uint32_t)(uintptr_t)l,
      16, 0, 0);
}

__device__ __forceinline__ unsigned short f2h_bits(float f) {
  _Float16 h = (_Float16)f;
  return __builtin_bit_cast(unsigned short, h);
}

// ---- Kernel 1: fp32 -> f16 convert + row squared-norms; also zeroes d_out ----
__global__ __launch_bounds__(256) void k_conv(const float* __restrict__ ide,
                                              const float* __restrict__ u,
                                              unsigned short* __restrict__ Ah,
                                              unsigned short* __restrict__ Bh,
                                              float* __restrict__ x2,
                                              float* __restrict__ y2,
                                              float* __restrict__ out0) {
  if (blockIdx.x == 0 && threadIdx.x == 0) *out0 = 0.f;
  int gw = (blockIdx.x * 256 + threadIdx.x) >> 6;
  int l  = threadIdx.x & 63;
  const float4* src;
  ushort4* dst;
  float* nrm;
  if (gw < N_IDE) {
    src = (const float4*)(ide + (size_t)gw * D_DIM);
    dst = (ushort4*)(Ah + (size_t)gw * D_DIM);
    nrm = x2 + gw;
  } else {
    int r = gw - N_IDE;
    src = (const float4*)(u + (size_t)r * D_DIM);
    dst = (ushort4*)(Bh + (size_t)r * D_DIM);
    nrm = y2 + r;
  }
  float4 v = src[l];
  float s = v.x * v.x + v.y * v.y + v.z * v.z + v.w * v.w;
  ushort4 o;
  o.x = f2h_bits(v.x); o.y = f2h_bits(v.y);
  o.z = f2h_bits(v.z); o.w = f2h_bits(v.w);
  dst[l] = o;
#pragma unroll
  for (int m = 1; m <= 32; m <<= 1) s += __shfl_xor(s, m, 64);
  if (l == 0) *nrm = s;
}

// ---- Kernel 2: barrier-free-K-loop MFMA GEMM ----
// grid (8, 32), 512 threads (8 waves = 2/SIMD).
// A: 128x256 f16 in LDS, fragment-major (every A-frag read = contiguous 1KB
//    ds_read_b128), staged ONCE via global_load_lds -> one barrier total.
// B: straight global->VGPR fragment loads (L2-resident, bx==XCD slice),
//    one-step-ahead register double buffer, no LDS, no barriers.
// Steps: s = cg*8 + kt, cg 0..3 (column groups of 512; cgi = cg*8+bx covers
// all 32 groups across the 8 bx slices), kt 0..7 (K=32 each) -> s in 0..31.
__global__ __launch_bounds__(512, 2) void k_gemm(const unsigned short* __restrict__ Ah,
                                                 const unsigned short* __restrict__ Bh,
                                                 const float* __restrict__ x2,
                                                 const float* __restrict__ y2,
                                                 float* __restrict__ partial) {
  __shared__ __align__(16) unsigned short sA[128 * 256];   // 64 KB, fragment-major
  __shared__ float rowacc[4][128];

  const int t    = threadIdx.x;
  const int w    = t >> 6;
  const int l    = t & 63;
  const int wm   = w >> 2, wn = w & 3;   // wave tile 64 rows x 128 cols
  const int lrow = l & 15;
  const int lhi  = l >> 4;
  const int bx   = blockIdx.x;           // 0..7 (column slice / XCD)
  const int by   = blockIdx.y;           // 0..31 (row group)

  rowacc[t >> 7][t & 127] = 0.f;

  // ---- stage A once, fragment-major: LDS chunk ((kt*8+m16)*64 + lane).
  // iteration i stages kt=i, wave w stages m16=w:
  //   source = A[by*128 + w*16 + lrow][ (i*4+lhi)*8 .. +8 ]
#pragma unroll
  for (int i = 0; i < 8; ++i)
    gll16(Ah + (size_t)(by * 128 + w * 16 + lrow) * D_DIM + (i * 4 + lhi) * 8,
          sA + (size_t)(i * 512 + w * 64) * 8);

  // ---- B fragment loader: global -> VGPR, this wave's 128 columns ----
  const unsigned short* Bbase = Bh + (size_t)(wn * 128 + lrow) * D_DIM + lhi * 8;
  auto loadB = [&](f16x8* buf, int s) {
    const int cgi = (s >> 3) * 8 + bx;
    const int kt  = s & 7;
    const unsigned short* p = Bbase + (size_t)cgi * 512 * D_DIM + kt * 32;
#pragma unroll
    for (int ni = 0; ni < 8; ++ni)
      buf[ni] = *(const f16x8*)(p + (size_t)ni * 16 * D_DIM);
  };

  float4 x2v[4];
#pragma unroll
  for (int mi = 0; mi < 4; ++mi)
    x2v[mi] = *(const float4*)&x2[by * 128 + wm * 64 + mi * 16 + lhi * 4];

  f16x8 bf0[8], bf1[8];
  loadB(bf0, 0);

  __syncthreads();   // A staged (vmcnt(0) drain); rowacc init visible

  for (int cg = 0; cg < 4; ++cg) {     // FIX: 4 column-groups per bx (was 8)
    const int cgi = cg * 8 + bx;

    f32x4 acc[4][8];
#pragma unroll
    for (int mi = 0; mi < 4; ++mi)
#pragma unroll
      for (int ni = 0; ni < 8; ++ni)
        acc[mi][ni] = (f32x4){0.f, 0.f, 0.f, 0.f};

    // one compute step: A frags from LDS (contiguous 1KB reads) + 32 MFMA
    auto step = [&](int kt, const f16x8* bf) {
      f16x8 af[4];
#pragma unroll
      for (int mi = 0; mi < 4; ++mi)
        af[mi] = *(const f16x8*)(sA + (size_t)(((kt * 8) + wm * 4 + mi) * 64 + l) * 8);
#pragma unroll
      for (int mi = 0; mi < 4; ++mi)
#pragma unroll
        for (int ni = 0; ni < 8; ++ni)
          acc[mi][ni] = __builtin_amdgcn_mfma_f32_16x16x32_f16(af[mi], bf[ni],
                                                               acc[mi][ni], 0, 0, 0);
    };

#pragma unroll
    for (int ktp = 0; ktp < 4; ++ktp) {
      const int s = cg * 8 + ktp * 2;
      loadB(bf1, s + 1);                       // prefetch odd step
      step(ktp * 2, bf0);
      loadB(bf0, (s + 2 < 32) ? s + 2 : 31);   // prefetch next even (clamped)
      step(ktp * 2 + 1, bf1);
    }

    // ---- epilogue: dist + row partial sums (overlaps other waves' MFMA) ----
    float yv[8];
#pragma unroll
    for (int ni = 0; ni < 8; ++ni)
      yv[ni] = y2[cgi * 512 + wn * 128 + ni * 16 + lrow];

#pragma unroll
    for (int mi = 0; mi < 4; ++mi) {
      float xr[4] = {x2v[mi].x, x2v[mi].y, x2v[mi].z, x2v[mi].w};
#pragma unroll
      for (int rr = 0; rr < 4; ++rr) {
        float ssum = 0.f;
#pragma unroll
        for (int ni = 0; ni < 8; ++ni) {
          float d2 = xr[rr] + yv[ni] - 2.0f * acc[mi][ni][rr];
          d2 = fmaxf(d2, 0.0f);
          ssum += __builtin_amdgcn_sqrtf(d2 + EPSF);
        }
        ssum += __shfl_xor(ssum, 1, 64);
        ssum += __shfl_xor(ssum, 2, 64);
        ssum += __shfl_xor(ssum, 4, 64);
        ssum += __shfl_xor(ssum, 8, 64);
        if (lrow == 0)
          rowacc[wn][wm * 64 + mi * 16 + lhi * 4 + rr] += ssum;  // disjoint slices
      }
    }
  }

  __syncthreads();
  if (t < 128)
    partial[(size_t)bx * N_IDE + by * 128 + t] =
        rowacc[0][t] + rowacc[1][t] + rowacc[2][t] + rowacc[3][t];
}

// ---- Kernel 3: loss = sum_{i,j} sqrt(((d_i-d_j))^2 + eps), d from partials ----
__global__ __launch_bounds__(256) void k_loss(const float* __restrict__ partial,
                                              float* __restrict__ out) {
  __shared__ float sd[N_IDE];
  __shared__ float wsum[4];
  int t = threadIdx.x;
  for (int k = t; k < N_IDE; k += 256) {
    float s = 0.f;
#pragma unroll
    for (int b = 0; b < 8; ++b) s += partial[(size_t)b * N_IDE + k];
    sd[k] = s;
  }
  __syncthreads();
  int tid = blockIdx.x * 256 + t;   // 65536 threads: 16 per i
  int i   = tid >> 4;
  int jl  = tid & 15;
  float di = sd[i];
  float s  = 0.f;
  for (int k = 0; k < 256; ++k) {
    float diff = (di - sd[jl + k * 16]) * INV_M;
    s += __builtin_amdgcn_sqrtf(diff * diff + EPSF);
  }
#pragma unroll
  for (int m = 1; m <= 32; m <<= 1) s += __shfl_xor(s, m, 64);
  if ((t & 63) == 0) wsum[t >> 6] = s;
  __syncthreads();
  if (t == 0) atomicAdd(out, wsum[0] + wsum[1] + wsum[2] + wsum[3]);
}

extern "C" void kernel_launch(void* const* d_in, const int* in_sizes, int n_in,
                              void* d_out, int out_size, void* d_ws, size_t ws_size,
                              hipStream_t stream) {
  (void)in_sizes; (void)n_in; (void)out_size; (void)ws_size;
  const float* ide = (const float*)d_in[0];
  const float* u   = (const float*)d_in[1];
  float* out = (float*)d_out;

  char* ws = (char*)d_ws;
  size_t off = 0;
  unsigned short* Ah = (unsigned short*)(ws + off); off += (size_t)N_IDE * D_DIM * 2;  // 2 MB
  unsigned short* Bh = (unsigned short*)(ws + off); off += (size_t)M_U  * D_DIM * 2;   // 8 MB
  float* x2      = (float*)(ws + off); off += (size_t)N_IDE * 4;
  float* y2      = (float*)(ws + off); off += (size_t)M_U * 4;
  float* partial = (float*)(ws + off); off += (size_t)8 * N_IDE * 4;                   // 128 KB

  k_conv<<<(N_IDE + M_U) / 4, 256, 0, stream>>>(ide, u, Ah, Bh, x2, y2, out);
  k_gemm<<<dim3(8, 32), 512, 0, stream>>>(Ah, Bh, x2, y2, partial);
  k_loss<<<256, 256, 0, stream>>>(partial, out);
}

// Round 6
// 147.883 us; speedup vs baseline: 1.2995x; 1.2995x over previous
//
#include <hip/hip_runtime.h>
#include <hip/hip_bf16.h>
#include <cstdint>

#define N_IDE 4096
#define M_U   16384
#define D_DIM 256
#define EPSF  1e-12f
#define INV_M (1.0f / 16384.0f)

typedef _Float16 f16x8 __attribute__((ext_vector_type(8)));
typedef float    f32x4 __attribute__((ext_vector_type(4)));

// ---- async global->LDS 16B copy. LDS dest = wave-uniform base + lane*16. ----
__device__ __forceinline__ void gll16(const void* g, void* l) {
  __builtin_amdgcn_global_load_lds(
      (const __attribute__((address_space(1))) void*)(uintptr_t)g,
      (__attribute__((address_space(3))) void*)(uint32_t)(uintptr_t)l,
      16, 0, 0);
}

__device__ __forceinline__ unsigned short f2h_bits(float f) {
  _Float16 h = (_Float16)f;
  return __builtin_bit_cast(unsigned short, h);
}

// ---- Kernel 1: fp32 -> f16 convert + row squared-norms; zeroes d_out ----
// A (ide) rows stored row-major. B (u) rows stored FRAGMENT-MAJOR:
//   16B chunk id = (group*8 + kt)*64 + lane, group = c>>4, kt = k>>5,
//   lane = ((k>>3)&3)*16 + (c&15)   [so a GEMM B-frag load is 1KB contiguous]
// Thread layout: one wave per row c; lane l holds k = 4l..4l+3.
//   -> lane = ((l>>1)&3)*16 + (c&15), kt = l>>3, 8B offset (l&1)*4 ushorts.
__global__ __launch_bounds__(256) void k_conv(const float* __restrict__ ide,
                                              const float* __restrict__ u,
                                              unsigned short* __restrict__ Ah,
                                              unsigned short* __restrict__ Bh,
                                              float* __restrict__ x2,
                                              float* __restrict__ y2,
                                              float* __restrict__ out0) {
  if (blockIdx.x == 0 && threadIdx.x == 0) *out0 = 0.f;
  int gw = (blockIdx.x * 256 + threadIdx.x) >> 6;
  int l  = threadIdx.x & 63;
  const float4* src;
  float* nrm;
  ushort4* dst;
  if (gw < N_IDE) {
    src = (const float4*)(ide + (size_t)gw * D_DIM);
    nrm = x2 + gw;
    dst = (ushort4*)(Ah + (size_t)gw * D_DIM) + l;           // row-major
  } else {
    int c = gw - N_IDE;
    src = (const float4*)(u + (size_t)c * D_DIM);
    nrm = y2 + c;
    size_t chunk = ((size_t)(c >> 4) * 8 + (l >> 3)) * 64 + ((l >> 1) & 3) * 16 + (c & 15);
    dst = (ushort4*)(Bh + chunk * 8 + (l & 1) * 4);          // fragment-major
  }
  float4 v = src[l];
  float s = v.x * v.x + v.y * v.y + v.z * v.z + v.w * v.w;
  ushort4 o;
  o.x = f2h_bits(v.x); o.y = f2h_bits(v.y);
  o.z = f2h_bits(v.z); o.w = f2h_bits(v.w);
  *dst = o;
#pragma unroll
  for (int m = 1; m <= 32; m <<= 1) s += __shfl_xor(s, m, 64);
  if (l == 0) *nrm = s;
}

// ---- Kernel 2: barrier-free-K-loop MFMA GEMM, wave tile 64x64 ----
// grid (8, 32), 512 threads (8 waves = 2/SIMD).
// A: 128x256 f16 in LDS fragment-major, staged ONCE -> one barrier.
// B: fragment-major global -> VGPR (1KB contiguous per frag load),
//    one-step-ahead register double buffer (32 VGPRs), no LDS, no barriers.
// Wave grid: wm = row-half (0..1), wn = col-quarter (0..3); block covers
// 128 rows x 256 cols per cg-pass; cg 0..7, kt 0..7 -> 64 flat steps.
// Register bill ~175 (acc 64 + bf 32 + af 16 + misc) -- fits 256 @ 2 w/SIMD.
__global__ __launch_bounds__(512, 2) void k_gemm(const unsigned short* __restrict__ Ah,
                                                 const unsigned short* __restrict__ Bh,
                                                 const float* __restrict__ x2,
                                                 const float* __restrict__ y2,
                                                 float* __restrict__ partial) {
  __shared__ __align__(16) unsigned short sA[128 * 256];   // 64 KB, fragment-major
  __shared__ float rowacc[4][128];

  const int t    = threadIdx.x;
  const int w    = t >> 6;
  const int l    = t & 63;
  const int wm   = w >> 2, wn = w & 3;   // wave tile 64 rows x 64 cols
  const int lrow = l & 15;
  const int lhi  = l >> 4;
  const int bx   = blockIdx.x;           // 0..7 (column slice / XCD)
  const int by   = blockIdx.y;           // 0..31 (row group)

  rowacc[t >> 7][t & 127] = 0.f;

  // ---- stage A once, fragment-major: chunk (kt*8 + m16)*64 + lane ----
#pragma unroll
  for (int i = 0; i < 8; ++i)
    gll16(Ah + (size_t)(by * 128 + w * 16 + lrow) * D_DIM + (i * 4 + lhi) * 8,
          sA + (size_t)(i * 512 + w * 64) * 8);

  // ---- B fragment loader: fragment-major global -> VGPR ----
  // frag(cgi, ni, kt) at ushort ((cgi*16 + wn*4 + ni)*8 + kt)*512 + l*8
  const unsigned short* Bbase = Bh + (size_t)(wn * 4) * 8 * 512 + (size_t)l * 8;
  auto loadB = [&](f16x8* buf, int s) {
    const int cgi = (s >> 3) * 8 + bx;   // column-group (256 cols) 0..63
    const int kt  = s & 7;
    const unsigned short* p = Bbase + ((size_t)cgi * 16 * 8 + kt) * 512;
#pragma unroll
    for (int ni = 0; ni < 4; ++ni)
      buf[ni] = *(const f16x8*)(p + (size_t)ni * 8 * 512);
  };

  float4 x2v[4];
#pragma unroll
  for (int mi = 0; mi < 4; ++mi)
    x2v[mi] = *(const float4*)&x2[by * 128 + wm * 64 + mi * 16 + lhi * 4];

  f16x8 bf0[4], bf1[4];
  loadB(bf0, 0);

  __syncthreads();   // A staged (vmcnt(0) drain); rowacc init visible

  for (int cg = 0; cg < 8; ++cg) {
    const int cgi = cg * 8 + bx;

    f32x4 acc[4][4];
#pragma unroll
    for (int mi = 0; mi < 4; ++mi)
#pragma unroll
      for (int ni = 0; ni < 4; ++ni)
        acc[mi][ni] = (f32x4){0.f, 0.f, 0.f, 0.f};

    // one step: 4 A-frag ds_read_b128 + 16 MFMA
    auto step = [&](int kt, const f16x8* bf) {
      f16x8 af[4];
#pragma unroll
      for (int mi = 0; mi < 4; ++mi)
        af[mi] = *(const f16x8*)(sA + (size_t)((kt * 8 + wm * 4 + mi) * 64 + l) * 8);
#pragma unroll
      for (int mi = 0; mi < 4; ++mi)
#pragma unroll
        for (int ni = 0; ni < 4; ++ni)
          acc[mi][ni] = __builtin_amdgcn_mfma_f32_16x16x32_f16(af[mi], bf[ni],
                                                               acc[mi][ni], 0, 0, 0);
    };

#pragma unroll
    for (int ktp = 0; ktp < 4; ++ktp) {
      const int s = cg * 8 + ktp * 2;
      loadB(bf1, s + 1);                       // prefetch odd step
      step(ktp * 2, bf0);
      loadB(bf0, (s + 2 < 64) ? s + 2 : 63);   // prefetch next even (clamped)
      step(ktp * 2 + 1, bf1);
    }

    // ---- epilogue: dist + row partial sums (overlaps other waves' MFMA) ----
    float yv[4];
#pragma unroll
    for (int ni = 0; ni < 4; ++ni)
      yv[ni] = y2[cgi * 256 + wn * 64 + ni * 16 + lrow];

#pragma unroll
    for (int mi = 0; mi < 4; ++mi) {
      float xr[4] = {x2v[mi].x, x2v[mi].y, x2v[mi].z, x2v[mi].w};
#pragma unroll
      for (int rr = 0; rr < 4; ++rr) {
        float ssum = 0.f;
#pragma unroll
        for (int ni = 0; ni < 4; ++ni) {
          float d2 = xr[rr] + yv[ni] - 2.0f * acc[mi][ni][rr];
          d2 = fmaxf(d2, 0.0f);
          ssum += __builtin_amdgcn_sqrtf(d2 + EPSF);
        }
        ssum += __shfl_xor(ssum, 1, 64);
        ssum += __shfl_xor(ssum, 2, 64);
        ssum += __shfl_xor(ssum, 4, 64);
        ssum += __shfl_xor(ssum, 8, 64);
        if (lrow == 0)
          rowacc[wn][wm * 64 + mi * 16 + lhi * 4 + rr] += ssum;  // disjoint per wave
      }
    }
  }

  __syncthreads();
  if (t < 128)
    partial[(size_t)bx * N_IDE + by * 128 + t] =
        rowacc[0][t] + rowacc[1][t] + rowacc[2][t] + rowacc[3][t];
}

// ---- Kernel 3: loss = sum_{i,j} sqrt(((d_i-d_j))^2 + eps), d from partials ----
__global__ __launch_bounds__(256) void k_loss(const float* __restrict__ partial,
                                              float* __restrict__ out) {
  __shared__ float sd[N_IDE];
  __shared__ float wsum[4];
  int t = threadIdx.x;
  for (int k = t; k < N_IDE; k += 256) {
    float s = 0.f;
#pragma unroll
    for (int b = 0; b < 8; ++b) s += partial[(size_t)b * N_IDE + k];
    sd[k] = s;
  }
  __syncthreads();
  int tid = blockIdx.x * 256 + t;   // 65536 threads: 16 per i
  int i   = tid >> 4;
  int jl  = tid & 15;
  float di = sd[i];
  float s  = 0.f;
  for (int k = 0; k < 256; ++k) {
    float diff = (di - sd[jl + k * 16]) * INV_M;
    s += __builtin_amdgcn_sqrtf(diff * diff + EPSF);
  }
#pragma unroll
  for (int m = 1; m <= 32; m <<= 1) s += __shfl_xor(s, m, 64);
  if ((t & 63) == 0) wsum[t >> 6] = s;
  __syncthreads();
  if (t == 0) atomicAdd(out, wsum[0] + wsum[1] + wsum[2] + wsum[3]);
}

extern "C" void kernel_launch(void* const* d_in, const int* in_sizes, int n_in,
                              void* d_out, int out_size, void* d_ws, size_t ws_size,
                              hipStream_t stream) {
  (void)in_sizes; (void)n_in; (void)out_size; (void)ws_size;
  const float* ide = (const float*)d_in[0];
  const float* u   = (const float*)d_in[1];
  float* out = (float*)d_out;

  char* ws = (char*)d_ws;
  size_t off = 0;
  unsigned short* Ah = (unsigned short*)(ws + off); off += (size_t)N_IDE * D_DIM * 2;  // 2 MB
  unsigned short* Bh = (unsigned short*)(ws + off); off += (size_t)M_U  * D_DIM * 2;   // 8 MB
  float* x2      = (float*)(ws + off); off += (size_t)N_IDE * 4;
  float* y2      = (float*)(ws + off); off += (size_t)M_U * 4;
  float* partial = (float*)(ws + off); off += (size_t)8 * N_IDE * 4;                   // 128 KB

  k_conv<<<(N_IDE + M_U) / 4, 256, 0, stream>>>(ide, u, Ah, Bh, x2, y2, out);
  k_gemm<<<dim3(8, 32), 512, 0, stream>>>(Ah, Bh, x2, y2, partial);
  k_loss<<<256, 256, 0, stream>>>(partial, out);
}